// Round 1
// baseline (248.761 us; speedup 1.0000x reference)
//
#include <hip/hip_runtime.h>
#include <stdint.h>

typedef __attribute__((ext_vector_type(8))) short short8;
typedef __attribute__((ext_vector_type(4))) float f32x4;

__device__ __forceinline__ unsigned short f2bf(float f) {
  union { float f; unsigned int u; } v; v.f = f;
  unsigned int r = v.u + 0x7fffu + ((v.u >> 16) & 1u);
  return (unsigned short)(r >> 16);
}

__device__ __forceinline__ uint32_t swz(uint32_t byteoff, uint32_t row) {
  return byteoff ^ ((row & 7u) << 4);
}

// ---------------------------------------------------------------------------
// Kernel 0: build relT (bf16, [64][4096], relT[e][k] = rel[k][e]) in ws,
//           zero the 1024-float accumulator region (pooled_sum + tree_emb).
// grid 64 x 256
// ---------------------------------------------------------------------------
__global__ void k_prep(const float* __restrict__ rel, unsigned short* __restrict__ relT,
                       float* __restrict__ accums) {
  __shared__ float tile[64][65];
  const int j = blockIdx.x;   // k-chunk of 64
  const int t = threadIdx.x;  // 0..255
#pragma unroll
  for (int p = 0; p < 16; ++p) {
    int elem = p * 256 + t;
    int kk = elem >> 6, ee = elem & 63;
    tile[kk][ee] = rel[(j * 64 + kk) * 64 + ee];
  }
  __syncthreads();
  const int e = t >> 2, chunk = t & 3;
  union { unsigned short u16[16]; uint4 v[2]; } tmp;
#pragma unroll
  for (int i = 0; i < 16; ++i) tmp.u16[i] = f2bf(tile[chunk * 16 + i][e]);
  unsigned short* dst = relT + e * 4096 + j * 64 + chunk * 16;
  *(uint4*)(dst) = tmp.v[0];
  *(uint4*)(dst + 8) = tmp.v[1];
  if (j == 0) {
    accums[t] = 0.f; accums[t + 256] = 0.f; accums[t + 512] = 0.f; accums[t + 768] = 0.f;
  }
}

// ---------------------------------------------------------------------------
// Kernel 1: support = link[b] @ rel  (bf16 MFMA, K=4096, N=64, 64-row tiles),
//           fused graph layer relu(support@GW + b) and column-sum into
//           pooled_sum[b][64] (mean is applied in k_final).
// grid 512 (8 batches x 64 row-blocks) x 256
// ---------------------------------------------------------------------------
struct StageMem { unsigned short a[64 * 64]; unsigned short bt[64 * 64]; };
union SupportSMem { StageMem s; float c[64 * 68]; };

__global__ __launch_bounds__(256, 2) void k_support(
    const float* __restrict__ link, const unsigned short* __restrict__ relT,
    const float* __restrict__ GW, const float* __restrict__ gbias,
    float* __restrict__ pooled_sum) {
  __shared__ SupportSMem sm;
  __shared__ float pool_red[4][64];

  const int t = threadIdx.x;
  const int lane = t & 63;
  const int wv = t >> 6;
  const int wrow = wv * 16;
  const int b = blockIdx.x >> 6;
  const int rowBase = (blockIdx.x & 63) * 64;

  const size_t linkBase = ((size_t)b << 24);  // b*4096*4096

  char* aBase = (char*)sm.s.a;
  char* bBase = (char*)sm.s.bt;

  f32x4 acc[4];
#pragma unroll
  for (int nt = 0; nt < 4; ++nt) acc[nt] = (f32x4){0.f, 0.f, 0.f, 0.f};

  // fragment read offsets (constant per thread)
  const int arow = wrow + (lane & 15);
  const uint32_t aoff0 = swz(arow * 128 + 0 * 64 + (lane >> 4) * 16, arow);
  const uint32_t aoff1 = swz(arow * 128 + 1 * 64 + (lane >> 4) * 16, arow);

  for (int k0 = 0; k0 < 4096; k0 += 64) {
    // ---- stage A tile: 64 rows x 64 k, fp32 -> bf16, swizzled LDS ----
#pragma unroll
    for (int p = 0; p < 4; ++p) {
      int row = p * 16 + (t >> 4);
      int quad = t & 15;
      const float4 v = *(const float4*)(link + linkBase + (size_t)(rowBase + row) * 4096 + k0 + quad * 4);
      union { unsigned short u16[4]; unsigned long long u64; } h;
      h.u16[0] = f2bf(v.x); h.u16[1] = f2bf(v.y); h.u16[2] = f2bf(v.z); h.u16[3] = f2bf(v.w);
      *(unsigned long long*)(aBase + swz(row * 128 + quad * 8, row)) = h.u64;
    }
    // ---- stage Bt tile: 64 n-rows x 64 k bf16 straight copy from relT ----
    {
      int n = t >> 2, seg = t & 3;
      const unsigned short* src = relT + n * 4096 + k0 + seg * 16;
      uint4 v0 = *(const uint4*)(src);
      uint4 v1 = *(const uint4*)(src + 8);
      uint32_t byteoff = n * 128 + seg * 32;
      *(uint4*)(bBase + swz(byteoff, n)) = v0;
      *(uint4*)(bBase + swz(byteoff + 16, n)) = v1;
    }
    __syncthreads();

    short8 afrag[2];
    afrag[0] = *(short8*)(aBase + aoff0);
    afrag[1] = *(short8*)(aBase + aoff1);
#pragma unroll
    for (int nt = 0; nt < 4; ++nt) {
      const int n = nt * 16 + (lane & 15);
#pragma unroll
      for (int kh = 0; kh < 2; ++kh) {
        short8 bfrag = *(short8*)(bBase + swz(n * 128 + kh * 64 + (lane >> 4) * 16, n));
        acc[nt] = __builtin_amdgcn_mfma_f32_16x16x32_bf16(afrag[kh], bfrag, acc[nt], 0, 0, 0);
      }
    }
    __syncthreads();
  }

  // ---- epilogue: C (64x64) -> LDS, graph layer, pooled partial sums ----
#pragma unroll
  for (int nt = 0; nt < 4; ++nt) {
#pragma unroll
    for (int j = 0; j < 4; ++j) {
      int row = wrow + (lane >> 4) * 4 + j;
      int col = nt * 16 + (lane & 15);
      sm.c[row * 68 + col] = acc[nt][j];
    }
  }
  __syncthreads();

  {
    const int e = t & 63;       // output-graph column
    const int rg = t >> 6;      // row group (== wave)
    float racc[16];
    const float gb = gbias[e];
#pragma unroll
    for (int r = 0; r < 16; ++r) racc[r] = gb;
    for (int i = 0; i < 64; ++i) {
      const float gw = GW[i * 64 + e];
#pragma unroll
      for (int r = 0; r < 16; ++r) racc[r] += sm.c[(rg * 16 + r) * 68 + i] * gw;
    }
    float p = 0.f;
#pragma unroll
    for (int r = 0; r < 16; ++r) p += fmaxf(racc[r], 0.f);
    pool_red[rg][e] = p;
  }
  __syncthreads();
  if (t < 64) {
    float s = pool_red[0][t] + pool_red[1][t] + pool_red[2][t] + pool_red[3][t];
    atomicAdd(&pooled_sum[b * 64 + t], s);
  }
}

// ---------------------------------------------------------------------------
// Kernel 2: 16-step attention scan per (b,t) tree. One wave per tree.
// grid 64 x 64
// ---------------------------------------------------------------------------
__global__ __launch_bounds__(64) void k_tree(
    const float* __restrict__ col_table, const float* __restrict__ rel_table,
    const float* __restrict__ Wk, const float* __restrict__ Wq, const float* __restrict__ Wv,
    const int* __restrict__ table_ids, const int* __restrict__ l_ids,
    const int* __restrict__ r_ids, float* __restrict__ tree_emb) {
  __shared__ float W[3][64][64];
  __shared__ float q[4][64];

  const int b = blockIdx.x >> 3;
  const int tt = blockIdx.x & 7;
  const int e = threadIdx.x;  // 0..63

  // stage Wk|Wq|Wv into LDS (flat, coalesced)
  float* Wf = (float*)W;
  for (int i = e; i < 3 * 4096; i += 64) {
    float v;
    if (i < 4096) v = Wk[i];
    else if (i < 8192) v = Wq[i - 4096];
    else v = Wv[i - 8192];
    Wf[i] = v;
  }
  __syncthreads();

  const int* tid = table_ids + (b * 8 + tt) * 17;
  const int* lid = l_ids + (b * 8 + tt) * 32;  // 16*2
  const int* rid = r_ids + (b * 8 + tt) * 32;

  float prev = rel_table[tid[0] * 64 + e];

  for (int d = 0; d < 16; ++d) {
    const int l0 = lid[d * 2], l1 = lid[d * 2 + 1];
    const int r0 = rid[d * 2], r1 = rid[d * 2 + 1];
    const float lce = 0.5f * (col_table[l0 * 64 + e] + col_table[l1 * 64 + e]);
    const float rce = 0.5f * (col_table[r0 * 64 + e] + col_table[r1 * 64 + e]);
    const float rte = rel_table[tid[1 + d] * 64 + e];
    q[0][e] = prev; q[1][e] = lce; q[2][e] = rce; q[3][e] = rte;
    __syncthreads();

    float K[4] = {0, 0, 0, 0}, Q[4] = {0, 0, 0, 0}, V[4] = {0, 0, 0, 0};
    for (int i = 0; i < 64; ++i) {
      const float q0 = q[0][i], q1 = q[1][i], q2 = q[2][i], q3 = q[3][i];
      const float wk = W[0][i][e], wq = W[1][i][e], wv = W[2][i][e];
      K[0] += q0 * wk; K[1] += q1 * wk; K[2] += q2 * wk; K[3] += q3 * wk;
      Q[0] += q0 * wq; Q[1] += q1 * wq; Q[2] += q2 * wq; Q[3] += q3 * wq;
      V[0] += q0 * wv; V[1] += q1 * wv; V[2] += q2 * wv; V[3] += q3 * wv;
    }

    // scores[j][k] = (Q[j] . K[k]) / 64 over the e dimension (64 lanes)
    float sc[4][4];
#pragma unroll
    for (int j = 0; j < 4; ++j) {
#pragma unroll
      for (int k = 0; k < 4; ++k) {
        float p = Q[j] * K[k];
#pragma unroll
        for (int off = 32; off >= 1; off >>= 1) p += __shfl_xor(p, off);
        sc[j][k] = p * (1.f / 64.f);
      }
    }

    // softmax over k, accumulate column weights w[k] = sum_j attn[j][k]
    float wsum[4] = {0, 0, 0, 0};
#pragma unroll
    for (int j = 0; j < 4; ++j) {
      float mx = fmaxf(fmaxf(sc[j][0], sc[j][1]), fmaxf(sc[j][2], sc[j][3]));
      float a0 = __expf(sc[j][0] - mx), a1 = __expf(sc[j][1] - mx);
      float a2 = __expf(sc[j][2] - mx), a3 = __expf(sc[j][3] - mx);
      float inv = 1.f / (a0 + a1 + a2 + a3);
      wsum[0] += a0 * inv; wsum[1] += a1 * inv; wsum[2] += a2 * inv; wsum[3] += a3 * inv;
    }

    prev = wsum[0] * V[0] + wsum[1] * V[1] + wsum[2] * V[2] + wsum[3] * V[3];
    __syncthreads();  // done reading q before next iteration overwrites it
  }

  atomicAdd(&tree_emb[b * 64 + e], prev);
}

// ---------------------------------------------------------------------------
// Kernel 3: logits = [pooled_sum/4096 || tree_emb] @ fc_w  + clip(log(mask))
// grid 128 x 256
// ---------------------------------------------------------------------------
__global__ void k_final(const float* __restrict__ action_mask, const float* __restrict__ fc_w,
                        const float* __restrict__ pooled_sum, const float* __restrict__ tree_emb,
                        float* __restrict__ out) {
  __shared__ float c[128];
  const int b = blockIdx.x >> 4;
  const int a = ((blockIdx.x & 15) << 8) + threadIdx.x;
  if (threadIdx.x < 128) {
    c[threadIdx.x] = (threadIdx.x < 64) ? pooled_sum[b * 64 + threadIdx.x] * (1.f / 4096.f)
                                        : tree_emb[b * 64 + threadIdx.x - 64];
  }
  __syncthreads();
  float acc = 0.f;
  for (int i = 0; i < 128; ++i) acc += c[i] * fc_w[i * 4096 + a];
  const float m = action_mask[b * 4096 + a];
  float lg = __logf(m);
  lg = fminf(fmaxf(lg, -3.4e38f), 3.4e38f);
  out[b * 4096 + a] = lg + acc;
}

// ---------------------------------------------------------------------------
extern "C" void kernel_launch(void* const* d_in, const int* in_sizes, int n_in,
                              void* d_out, int out_size, void* d_ws, size_t ws_size,
                              hipStream_t stream) {
  const float* link = (const float*)d_in[0];
  const float* mask = (const float*)d_in[1];
  const float* col = (const float*)d_in[2];
  const float* rel = (const float*)d_in[3];
  const float* GW = (const float*)d_in[4];
  const float* gb = (const float*)d_in[5];
  const float* Wk = (const float*)d_in[6];
  const float* Wq = (const float*)d_in[7];
  const float* Wv = (const float*)d_in[8];
  const float* fcw = (const float*)d_in[9];
  const int* tids = (const int*)d_in[10];
  const int* lids = (const int*)d_in[11];
  const int* rids = (const int*)d_in[12];
  float* out = (float*)d_out;

  unsigned short* relT = (unsigned short*)d_ws;               // 64*4096 bf16 = 512 KB
  float* accums = (float*)((char*)d_ws + 64 * 4096 * 2);      // 1024 floats
  float* pooled_sum = accums;                                 // [8][64]
  float* tree = accums + 512;                                 // [8][64]

  hipLaunchKernelGGL(k_prep, dim3(64), dim3(256), 0, stream, rel, relT, accums);
  hipLaunchKernelGGL(k_support, dim3(512), dim3(256), 0, stream, link, relT, GW, gb, pooled_sum);
  hipLaunchKernelGGL(k_tree, dim3(64), dim3(64), 0, stream, col, rel, Wk, Wq, Wv, tids, lids, rids, tree);
  hipLaunchKernelGGL(k_final, dim3(128), dim3(256), 0, stream, mask, fcw, pooled_sum, tree, out);
}

// Round 2
// 222.773 us; speedup vs baseline: 1.1167x; 1.1167x over previous
//
#include <hip/hip_runtime.h>
#include <hip/hip_bf16.h>
#include <stdint.h>

typedef __attribute__((ext_vector_type(8))) short short8;
typedef __attribute__((ext_vector_type(4))) float f32x4;

union FragU { short8 s; __hip_bfloat162 h[4]; };
union BU { uint4 u; short8 s; };

__device__ __forceinline__ unsigned short f2bf(float f) {
  union { float f; unsigned int u; } v; v.f = f;
  unsigned int r = v.u + 0x7fffu + ((v.u >> 16) & 1u);
  return (unsigned short)(r >> 16);
}

// ---------------------------------------------------------------------------
// Kernel 0: relT[e][k] = bf16(rel[k][e])  (64 x 4096), zero accumulators.
// grid 64 x 256
// ---------------------------------------------------------------------------
__global__ void k_prep(const float* __restrict__ rel, unsigned short* __restrict__ relT,
                       float* __restrict__ accums) {
  __shared__ float tile[64][65];
  const int j = blockIdx.x;
  const int t = threadIdx.x;
#pragma unroll
  for (int p = 0; p < 16; ++p) {
    int elem = p * 256 + t;
    int kk = elem >> 6, ee = elem & 63;
    tile[kk][ee] = rel[(j * 64 + kk) * 64 + ee];
  }
  __syncthreads();
  const int e = t >> 2, chunk = t & 3;
  union { unsigned short u16[16]; uint4 v[2]; } tmp;
#pragma unroll
  for (int i = 0; i < 16; ++i) tmp.u16[i] = f2bf(tile[chunk * 16 + i][e]);
  unsigned short* dst = relT + e * 4096 + j * 64 + chunk * 16;
  *(uint4*)(dst) = tmp.v[0];
  *(uint4*)(dst + 8) = tmp.v[1];
  if (j == 0) {
    accums[t] = 0.f; accums[t + 256] = 0.f; accums[t + 512] = 0.f; accums[t + 768] = 0.f;
  }
}

// ---------------------------------------------------------------------------
// Fused main kernel.
//   blocks 0..15   : tree attention (4 trees per block, one per wave)
//   blocks 16..527 : support GEMM (barrier-free, reg-staged) + graph epilogue
// ---------------------------------------------------------------------------
#define LOADK(Va, Vb, kk) do {                                        \
    const float* _ap = aptr + (kk);                                   \
    Va[0] = *(const float4*)(_ap);                                    \
    Va[1] = *(const float4*)(_ap + 4);                                \
    Va[2] = *(const float4*)(_ap + 32);                               \
    Va[3] = *(const float4*)(_ap + 36);                               \
    _Pragma("unroll")                                                 \
    for (int nt = 0; nt < 4; ++nt) {                                  \
      Vb[nt * 2]     = *(const uint4*)(bptr[nt] + (kk));              \
      Vb[nt * 2 + 1] = *(const uint4*)(bptr[nt] + (kk) + 32);         \
    }                                                                 \
  } while (0)

#define COMPK(Va, Vb) do {                                            \
    FragU f0, f1;                                                     \
    f0.h[0] = __float22bfloat162_rn(float2{Va[0].x, Va[0].y});        \
    f0.h[1] = __float22bfloat162_rn(float2{Va[0].z, Va[0].w});        \
    f0.h[2] = __float22bfloat162_rn(float2{Va[1].x, Va[1].y});        \
    f0.h[3] = __float22bfloat162_rn(float2{Va[1].z, Va[1].w});        \
    f1.h[0] = __float22bfloat162_rn(float2{Va[2].x, Va[2].y});        \
    f1.h[1] = __float22bfloat162_rn(float2{Va[2].z, Va[2].w});        \
    f1.h[2] = __float22bfloat162_rn(float2{Va[3].x, Va[3].y});        \
    f1.h[3] = __float22bfloat162_rn(float2{Va[3].z, Va[3].w});        \
    _Pragma("unroll")                                                 \
    for (int nt = 0; nt < 4; ++nt) {                                  \
      BU b0, b1; b0.u = Vb[nt * 2]; b1.u = Vb[nt * 2 + 1];            \
      acc[nt] = __builtin_amdgcn_mfma_f32_16x16x32_bf16(f0.s, b0.s, acc[nt], 0, 0, 0); \
      acc[nt] = __builtin_amdgcn_mfma_f32_16x16x32_bf16(f1.s, b1.s, acc[nt], 0, 0, 0); \
    }                                                                 \
  } while (0)

__global__ __launch_bounds__(256, 2) void k_main(
    const float* __restrict__ link, const unsigned short* __restrict__ relT,
    const float* __restrict__ GW, const float* __restrict__ gbias,
    float* __restrict__ pooled_sum,
    const float* __restrict__ col_table, const float* __restrict__ rel_table,
    const float* __restrict__ Wk, const float* __restrict__ Wq, const float* __restrict__ Wv,
    const int* __restrict__ table_ids, const int* __restrict__ l_ids,
    const int* __restrict__ r_ids, float* __restrict__ tree_emb) {
  __shared__ union {
    struct { float wpk[64 * 64 * 4]; float qT[4][64][4]; } tr;   // 68 KB
    struct { float c[64 * 68]; float pr[4][64]; } su;            // 18.4 KB
  } sm;

  const int t = threadIdx.x;
  const int lane = t & 63;
  const int wv = t >> 6;

  if (blockIdx.x < 16) {
    // ------------------------- tree branch -------------------------
    const int e = lane;
    // stage Wpk[i][e][4] = {Wk, Wq, Wv, 0}
#pragma unroll 4
    for (int ii = 0; ii < 16; ++ii) {
      int i = ii * 4 + wv;
      float4 w;
      w.x = Wk[i * 64 + e]; w.y = Wq[i * 64 + e]; w.z = Wv[i * 64 + e]; w.w = 0.f;
      *(float4*)&sm.tr.wpk[(i * 64 + e) * 4] = w;
    }
    __syncthreads();

    const int tree = blockIdx.x * 4 + wv;   // 0..63
    const int b = tree >> 3;
    const int* tid = table_ids + tree * 17;
    const int* lid = l_ids + tree * 32;
    const int* rid = r_ids + tree * 32;

    float prev = rel_table[tid[0] * 64 + e];

    for (int d = 0; d < 16; ++d) {
      const int l0 = lid[d * 2], l1 = lid[d * 2 + 1];
      const int r0 = rid[d * 2], r1 = rid[d * 2 + 1];
      const float lce = 0.5f * (col_table[l0 * 64 + e] + col_table[l1 * 64 + e]);
      const float rce = 0.5f * (col_table[r0 * 64 + e] + col_table[r1 * 64 + e]);
      const float rte = rel_table[tid[1 + d] * 64 + e];
      float4 qv0; qv0.x = prev; qv0.y = lce; qv0.z = rce; qv0.w = rte;
      *(float4*)&sm.tr.qT[wv][e][0] = qv0;
      __syncthreads();

      float K[4] = {0, 0, 0, 0}, Q[4] = {0, 0, 0, 0}, V[4] = {0, 0, 0, 0};
      const float* wbase = &sm.tr.wpk[e * 4];
#pragma unroll 8
      for (int i = 0; i < 64; ++i) {
        f32x4 qv = *(const f32x4*)&sm.tr.qT[wv][i][0];
        f32x4 w = *(const f32x4*)&wbase[i * 256];
#pragma unroll
        for (int j = 0; j < 4; ++j) {
          K[j] += qv[j] * w[0];
          Q[j] += qv[j] * w[1];
          V[j] += qv[j] * w[2];
        }
      }

      float sc[4][4];
#pragma unroll
      for (int j = 0; j < 4; ++j)
#pragma unroll
        for (int k = 0; k < 4; ++k) {
          float p = Q[j] * K[k];
          p += __shfl_xor(p, 1);  p += __shfl_xor(p, 2);  p += __shfl_xor(p, 4);
          p += __shfl_xor(p, 8);  p += __shfl_xor(p, 16); p += __shfl_xor(p, 32);
          sc[j][k] = p * (1.f / 64.f);
        }

      float wsum[4] = {0, 0, 0, 0};
#pragma unroll
      for (int j = 0; j < 4; ++j) {
        float mx = fmaxf(fmaxf(sc[j][0], sc[j][1]), fmaxf(sc[j][2], sc[j][3]));
        float a0 = __expf(sc[j][0] - mx), a1 = __expf(sc[j][1] - mx);
        float a2 = __expf(sc[j][2] - mx), a3 = __expf(sc[j][3] - mx);
        float inv = 1.f / (a0 + a1 + a2 + a3);
        wsum[0] += a0 * inv; wsum[1] += a1 * inv; wsum[2] += a2 * inv; wsum[3] += a3 * inv;
      }

      prev = wsum[0] * V[0] + wsum[1] * V[1] + wsum[2] * V[2] + wsum[3] * V[3];
      __syncthreads();
    }
    atomicAdd(&tree_emb[b * 64 + e], prev);
  } else {
    // ------------------------ support branch ------------------------
    const int sblk = blockIdx.x - 16;
    const int b = sblk >> 6;
    const int rowBase = (sblk & 63) * 64;
    const int wrow = wv * 16;
    const int g = lane >> 4;   // k-group
    const int r = lane & 15;   // row within fragment

    const float* aptr = link + ((size_t)b << 24) + (size_t)(rowBase + wrow + r) * 4096 + g * 8;
    const unsigned short* bptr[4];
#pragma unroll
    for (int nt = 0; nt < 4; ++nt) bptr[nt] = relT + (size_t)(nt * 16 + r) * 4096 + g * 8;

    f32x4 acc[4];
#pragma unroll
    for (int nt = 0; nt < 4; ++nt) acc[nt] = (f32x4){0.f, 0.f, 0.f, 0.f};

    float4 Xa[4], Ya[4];
    uint4 Xb[8], Yb[8];

    LOADK(Xa, Xb, 0);
    for (int k0 = 0; k0 < 4096; k0 += 128) {
      LOADK(Ya, Yb, (k0 + 64) & 4095);
      COMPK(Xa, Xb);
      LOADK(Xa, Xb, (k0 + 128) & 4095);
      COMPK(Ya, Yb);
    }

    // epilogue: C -> LDS, graph layer relu(C@GW + b), column partial sums
#pragma unroll
    for (int nt = 0; nt < 4; ++nt)
#pragma unroll
      for (int j = 0; j < 4; ++j)
        sm.su.c[(wrow + (lane >> 4) * 4 + j) * 68 + nt * 16 + (lane & 15)] = acc[nt][j];
    __syncthreads();

    {
      const int e = lane;
      float racc[16];
      const float gb = gbias[e];
#pragma unroll
      for (int rr = 0; rr < 16; ++rr) racc[rr] = gb;
      for (int i4 = 0; i4 < 16; ++i4) {
        const float g0 = GW[(i4 * 4 + 0) * 64 + e];
        const float g1 = GW[(i4 * 4 + 1) * 64 + e];
        const float g2 = GW[(i4 * 4 + 2) * 64 + e];
        const float g3 = GW[(i4 * 4 + 3) * 64 + e];
#pragma unroll
        for (int rr = 0; rr < 16; ++rr) {
          f32x4 cb = *(const f32x4*)&sm.su.c[(wrow + rr) * 68 + i4 * 4];
          racc[rr] += cb[0] * g0 + cb[1] * g1 + cb[2] * g2 + cb[3] * g3;
        }
      }
      float p = 0.f;
#pragma unroll
      for (int rr = 0; rr < 16; ++rr) p += fmaxf(racc[rr], 0.f);
      sm.su.pr[wv][e] = p;
    }
    __syncthreads();
    if (t < 64) {
      float s = sm.su.pr[0][t] + sm.su.pr[1][t] + sm.su.pr[2][t] + sm.su.pr[3][t];
      atomicAdd(&pooled_sum[b * 64 + t], s);
    }
  }
}

// ---------------------------------------------------------------------------
// Kernel 3: logits = [pooled_sum/4096 || tree_emb] @ fc_w  + clip(log(mask))
// grid 128 x 256
// ---------------------------------------------------------------------------
__global__ void k_final(const float* __restrict__ action_mask, const float* __restrict__ fc_w,
                        const float* __restrict__ pooled_sum, const float* __restrict__ tree_emb,
                        float* __restrict__ out) {
  __shared__ float c[128];
  const int b = blockIdx.x >> 4;
  const int a = ((blockIdx.x & 15) << 8) + threadIdx.x;
  if (threadIdx.x < 128) {
    c[threadIdx.x] = (threadIdx.x < 64) ? pooled_sum[b * 64 + threadIdx.x] * (1.f / 4096.f)
                                        : tree_emb[b * 64 + threadIdx.x - 64];
  }
  __syncthreads();
  float acc = 0.f;
  for (int i = 0; i < 128; ++i) acc += c[i] * fc_w[i * 4096 + a];
  const float m = action_mask[b * 4096 + a];
  float lg = __logf(m);
  lg = fminf(fmaxf(lg, -3.4e38f), 3.4e38f);
  out[b * 4096 + a] = lg + acc;
}

// ---------------------------------------------------------------------------
extern "C" void kernel_launch(void* const* d_in, const int* in_sizes, int n_in,
                              void* d_out, int out_size, void* d_ws, size_t ws_size,
                              hipStream_t stream) {
  const float* link = (const float*)d_in[0];
  const float* mask = (const float*)d_in[1];
  const float* col = (const float*)d_in[2];
  const float* rel = (const float*)d_in[3];
  const float* GW = (const float*)d_in[4];
  const float* gb = (const float*)d_in[5];
  const float* Wk = (const float*)d_in[6];
  const float* Wq = (const float*)d_in[7];
  const float* Wv = (const float*)d_in[8];
  const float* fcw = (const float*)d_in[9];
  const int* tids = (const int*)d_in[10];
  const int* lids = (const int*)d_in[11];
  const int* rids = (const int*)d_in[12];
  float* out = (float*)d_out;

  unsigned short* relT = (unsigned short*)d_ws;            // 512 KB
  float* accums = (float*)((char*)d_ws + 64 * 4096 * 2);   // 1024 floats
  float* pooled_sum = accums;                              // [8][64]
  float* tree = accums + 512;                              // [8][64]

  hipLaunchKernelGGL(k_prep, dim3(64), dim3(256), 0, stream, rel, relT, accums);
  hipLaunchKernelGGL(k_main, dim3(528), dim3(256), 0, stream,
                     link, relT, GW, gb, pooled_sum,
                     col, rel, Wk, Wq, Wv, tids, lids, rids, tree);
  hipLaunchKernelGGL(k_final, dim3(128), dim3(256), 0, stream, mask, fcw, pooled_sum, tree, out);
}

// Round 3
// 215.576 us; speedup vs baseline: 1.1539x; 1.0334x over previous
//
#include <hip/hip_runtime.h>
#include <hip/hip_bf16.h>
#include <stdint.h>

typedef __attribute__((ext_vector_type(8))) short short8;
typedef __attribute__((ext_vector_type(4))) float f32x4;

union FragU { short8 s; __hip_bfloat162 h[4]; };
union BU { uint4 u; short8 s; };

__device__ __forceinline__ unsigned short f2bf(float f) {
  union { float f; unsigned int u; } v; v.f = f;
  unsigned int r = v.u + 0x7fffu + ((v.u >> 16) & 1u);
  return (unsigned short)(r >> 16);
}

// ---------------------------------------------------------------------------
// Kernel 0: relT[e][k] = bf16(rel[k][e])  (64 x 4096), zero accumulators.
// grid 64 x 256
// ---------------------------------------------------------------------------
__global__ void k_prep(const float* __restrict__ rel, unsigned short* __restrict__ relT,
                       float* __restrict__ accums) {
  __shared__ float tile[64][65];
  const int j = blockIdx.x;
  const int t = threadIdx.x;
#pragma unroll
  for (int p = 0; p < 16; ++p) {
    int elem = p * 256 + t;
    int kk = elem >> 6, ee = elem & 63;
    tile[kk][ee] = rel[(j * 64 + kk) * 64 + ee];
  }
  __syncthreads();
  const int e = t >> 2, chunk = t & 3;
  union { unsigned short u16[16]; uint4 v[2]; } tmp;
#pragma unroll
  for (int i = 0; i < 16; ++i) tmp.u16[i] = f2bf(tile[chunk * 16 + i][e]);
  unsigned short* dst = relT + e * 4096 + j * 64 + chunk * 16;
  *(uint4*)(dst) = tmp.v[0];
  *(uint4*)(dst + 8) = tmp.v[1];
  if (j == 0) {
    accums[t] = 0.f; accums[t + 256] = 0.f; accums[t + 512] = 0.f; accums[t + 768] = 0.f;
  }
}

// ---------------------------------------------------------------------------
// Fused main kernel.
//   blocks 0..15   : tree attention (4 trees per block, one per wave)
//   blocks 16..527 : support GEMM (barrier-free, reg-staged) + graph epilogue
// A (link) loads are NON-TEMPORAL: zero reuse, keep L1/L2 for relT (B).
// ---------------------------------------------------------------------------
#define LOADK(Va, Vb, kk) do {                                        \
    const float* _ap = aptr + (kk);                                   \
    Va[0] = __builtin_nontemporal_load((const f32x4*)(_ap));          \
    Va[1] = __builtin_nontemporal_load((const f32x4*)(_ap + 4));      \
    Va[2] = __builtin_nontemporal_load((const f32x4*)(_ap + 32));     \
    Va[3] = __builtin_nontemporal_load((const f32x4*)(_ap + 36));     \
    _Pragma("unroll")                                                 \
    for (int nt = 0; nt < 4; ++nt) {                                  \
      Vb[nt * 2]     = *(const uint4*)(bptr[nt] + (kk));              \
      Vb[nt * 2 + 1] = *(const uint4*)(bptr[nt] + (kk) + 32);         \
    }                                                                 \
  } while (0)

#define COMPK(Va, Vb) do {                                            \
    FragU f0, f1;                                                     \
    f0.h[0] = __float22bfloat162_rn(float2{Va[0][0], Va[0][1]});      \
    f0.h[1] = __float22bfloat162_rn(float2{Va[0][2], Va[0][3]});      \
    f0.h[2] = __float22bfloat162_rn(float2{Va[1][0], Va[1][1]});      \
    f0.h[3] = __float22bfloat162_rn(float2{Va[1][2], Va[1][3]});      \
    f1.h[0] = __float22bfloat162_rn(float2{Va[2][0], Va[2][1]});      \
    f1.h[1] = __float22bfloat162_rn(float2{Va[2][2], Va[2][3]});      \
    f1.h[2] = __float22bfloat162_rn(float2{Va[3][0], Va[3][1]});      \
    f1.h[3] = __float22bfloat162_rn(float2{Va[3][2], Va[3][3]});      \
    _Pragma("unroll")                                                 \
    for (int nt = 0; nt < 4; ++nt) {                                  \
      BU b0, b1; b0.u = Vb[nt * 2]; b1.u = Vb[nt * 2 + 1];            \
      acc[nt] = __builtin_amdgcn_mfma_f32_16x16x32_bf16(f0.s, b0.s, acc[nt], 0, 0, 0); \
      acc[nt] = __builtin_amdgcn_mfma_f32_16x16x32_bf16(f1.s, b1.s, acc[nt], 0, 0, 0); \
    }                                                                 \
  } while (0)

__global__ __launch_bounds__(256, 2) void k_main(
    const float* __restrict__ link, const unsigned short* __restrict__ relT,
    const float* __restrict__ GW, const float* __restrict__ gbias,
    float* __restrict__ pooled_sum,
    const float* __restrict__ col_table, const float* __restrict__ rel_table,
    const float* __restrict__ Wk, const float* __restrict__ Wq, const float* __restrict__ Wv,
    const int* __restrict__ table_ids, const int* __restrict__ l_ids,
    const int* __restrict__ r_ids, float* __restrict__ tree_emb) {
  __shared__ union {
    struct { float wpk[64 * 64 * 4]; float qT[4][64][4]; } tr;   // 68 KB
    struct { float c[64 * 68]; float pr[4][64]; } su;            // 18.4 KB
  } sm;

  const int t = threadIdx.x;
  const int lane = t & 63;
  const int wv = t >> 6;

  if (blockIdx.x < 16) {
    // ------------------------- tree branch -------------------------
    const int e = lane;
#pragma unroll 4
    for (int ii = 0; ii < 16; ++ii) {
      int i = ii * 4 + wv;
      float4 w;
      w.x = Wk[i * 64 + e]; w.y = Wq[i * 64 + e]; w.z = Wv[i * 64 + e]; w.w = 0.f;
      *(float4*)&sm.tr.wpk[(i * 64 + e) * 4] = w;
    }
    __syncthreads();

    const int tree = blockIdx.x * 4 + wv;   // 0..63
    const int b = tree >> 3;
    const int* tid = table_ids + tree * 17;
    const int* lid = l_ids + tree * 32;
    const int* rid = r_ids + tree * 32;

    float prev = rel_table[tid[0] * 64 + e];

    for (int d = 0; d < 16; ++d) {
      const int l0 = lid[d * 2], l1 = lid[d * 2 + 1];
      const int r0 = rid[d * 2], r1 = rid[d * 2 + 1];
      const float lce = 0.5f * (col_table[l0 * 64 + e] + col_table[l1 * 64 + e]);
      const float rce = 0.5f * (col_table[r0 * 64 + e] + col_table[r1 * 64 + e]);
      const float rte = rel_table[tid[1 + d] * 64 + e];
      float4 qv0; qv0.x = prev; qv0.y = lce; qv0.z = rce; qv0.w = rte;
      *(float4*)&sm.tr.qT[wv][e][0] = qv0;
      __syncthreads();

      float K[4] = {0, 0, 0, 0}, Q[4] = {0, 0, 0, 0}, V[4] = {0, 0, 0, 0};
      const float* wbase = &sm.tr.wpk[e * 4];
#pragma unroll 8
      for (int i = 0; i < 64; ++i) {
        f32x4 qv = *(const f32x4*)&sm.tr.qT[wv][i][0];
        f32x4 w = *(const f32x4*)&wbase[i * 256];
#pragma unroll
        for (int j = 0; j < 4; ++j) {
          K[j] += qv[j] * w[0];
          Q[j] += qv[j] * w[1];
          V[j] += qv[j] * w[2];
        }
      }

      float sc[4][4];
#pragma unroll
      for (int j = 0; j < 4; ++j)
#pragma unroll
        for (int k = 0; k < 4; ++k) {
          float p = Q[j] * K[k];
          p += __shfl_xor(p, 1);  p += __shfl_xor(p, 2);  p += __shfl_xor(p, 4);
          p += __shfl_xor(p, 8);  p += __shfl_xor(p, 16); p += __shfl_xor(p, 32);
          sc[j][k] = p * (1.f / 64.f);
        }

      float wsum[4] = {0, 0, 0, 0};
#pragma unroll
      for (int j = 0; j < 4; ++j) {
        float mx = fmaxf(fmaxf(sc[j][0], sc[j][1]), fmaxf(sc[j][2], sc[j][3]));
        float a0 = __expf(sc[j][0] - mx), a1 = __expf(sc[j][1] - mx);
        float a2 = __expf(sc[j][2] - mx), a3 = __expf(sc[j][3] - mx);
        float inv = 1.f / (a0 + a1 + a2 + a3);
        wsum[0] += a0 * inv; wsum[1] += a1 * inv; wsum[2] += a2 * inv; wsum[3] += a3 * inv;
      }

      prev = wsum[0] * V[0] + wsum[1] * V[1] + wsum[2] * V[2] + wsum[3] * V[3];
      __syncthreads();
    }
    atomicAdd(&tree_emb[b * 64 + e], prev);
  } else {
    // ------------------------ support branch ------------------------
    const int sblk = blockIdx.x - 16;
    const int b = sblk >> 6;
    const int rowBase = (sblk & 63) * 64;
    const int wrow = wv * 16;
    const int g = lane >> 4;   // k-group
    const int r = lane & 15;   // row within fragment

    const float* aptr = link + ((size_t)b << 24) + (size_t)(rowBase + wrow + r) * 4096 + g * 8;
    const unsigned short* bptr[4];
#pragma unroll
    for (int nt = 0; nt < 4; ++nt) bptr[nt] = relT + (size_t)(nt * 16 + r) * 4096 + g * 8;

    f32x4 acc[4];
#pragma unroll
    for (int nt = 0; nt < 4; ++nt) acc[nt] = (f32x4){0.f, 0.f, 0.f, 0.f};

    f32x4 Xa[4], Ya[4];
    uint4 Xb[8], Yb[8];

    LOADK(Xa, Xb, 0);
    for (int k0 = 0; k0 < 4096; k0 += 128) {
      LOADK(Ya, Yb, (k0 + 64) & 4095);
      COMPK(Xa, Xb);
      LOADK(Xa, Xb, (k0 + 128) & 4095);
      COMPK(Ya, Yb);
    }

    // epilogue: C -> LDS, graph layer relu(C@GW + b), column partial sums
#pragma unroll
    for (int nt = 0; nt < 4; ++nt)
#pragma unroll
      for (int j = 0; j < 4; ++j)
        sm.su.c[(wrow + (lane >> 4) * 4 + j) * 68 + nt * 16 + (lane & 15)] = acc[nt][j];
    __syncthreads();

    {
      const int e = lane;
      float racc[16];
      const float gb = gbias[e];
#pragma unroll
      for (int rr = 0; rr < 16; ++rr) racc[rr] = gb;
      for (int i4 = 0; i4 < 16; ++i4) {
        const float g0 = GW[(i4 * 4 + 0) * 64 + e];
        const float g1 = GW[(i4 * 4 + 1) * 64 + e];
        const float g2 = GW[(i4 * 4 + 2) * 64 + e];
        const float g3 = GW[(i4 * 4 + 3) * 64 + e];
#pragma unroll
        for (int rr = 0; rr < 16; ++rr) {
          f32x4 cb = *(const f32x4*)&sm.su.c[(wrow + rr) * 68 + i4 * 4];
          racc[rr] += cb[0] * g0 + cb[1] * g1 + cb[2] * g2 + cb[3] * g3;
        }
      }
      float p = 0.f;
#pragma unroll
      for (int rr = 0; rr < 16; ++rr) p += fmaxf(racc[rr], 0.f);
      sm.su.pr[wv][e] = p;
    }
    __syncthreads();
    if (t < 64) {
      float s = sm.su.pr[0][t] + sm.su.pr[1][t] + sm.su.pr[2][t] + sm.su.pr[3][t];
      atomicAdd(&pooled_sum[b * 64 + t], s);
    }
  }
}

// ---------------------------------------------------------------------------
// Kernel 3: logits = [pooled_sum/4096 || tree_emb] @ fc_w  + clip(log(mask))
// grid 128 x 256
// ---------------------------------------------------------------------------
__global__ void k_final(const float* __restrict__ action_mask, const float* __restrict__ fc_w,
                        const float* __restrict__ pooled_sum, const float* __restrict__ tree_emb,
                        float* __restrict__ out) {
  __shared__ float c[128];
  const int b = blockIdx.x >> 4;
  const int a = ((blockIdx.x & 15) << 8) + threadIdx.x;
  if (threadIdx.x < 128) {
    c[threadIdx.x] = (threadIdx.x < 64) ? pooled_sum[b * 64 + threadIdx.x] * (1.f / 4096.f)
                                        : tree_emb[b * 64 + threadIdx.x - 64];
  }
  __syncthreads();
  float acc = 0.f;
  for (int i = 0; i < 128; ++i) acc += c[i] * fc_w[i * 4096 + a];
  const float m = action_mask[b * 4096 + a];
  float lg = __logf(m);
  lg = fminf(fmaxf(lg, -3.4e38f), 3.4e38f);
  out[b * 4096 + a] = lg + acc;
}

// ---------------------------------------------------------------------------
extern "C" void kernel_launch(void* const* d_in, const int* in_sizes, int n_in,
                              void* d_out, int out_size, void* d_ws, size_t ws_size,
                              hipStream_t stream) {
  const float* link = (const float*)d_in[0];
  const float* mask = (const float*)d_in[1];
  const float* col = (const float*)d_in[2];
  const float* rel = (const float*)d_in[3];
  const float* GW = (const float*)d_in[4];
  const float* gb = (const float*)d_in[5];
  const float* Wk = (const float*)d_in[6];
  const float* Wq = (const float*)d_in[7];
  const float* Wv = (const float*)d_in[8];
  const float* fcw = (const float*)d_in[9];
  const int* tids = (const int*)d_in[10];
  const int* lids = (const int*)d_in[11];
  const int* rids = (const int*)d_in[12];
  float* out = (float*)d_out;

  unsigned short* relT = (unsigned short*)d_ws;            // 512 KB
  float* accums = (float*)((char*)d_ws + 64 * 4096 * 2);   // 1024 floats
  float* pooled_sum = accums;                              // [8][64]
  float* tree = accums + 512;                              // [8][64]

  hipLaunchKernelGGL(k_prep, dim3(64), dim3(256), 0, stream, rel, relT, accums);
  hipLaunchKernelGGL(k_main, dim3(528), dim3(256), 0, stream,
                     link, relT, GW, gb, pooled_sum,
                     col, rel, Wk, Wq, Wv, tids, lids, rids, tree);
  hipLaunchKernelGGL(k_final, dim3(128), dim3(256), 0, stream, mask, fcw, pooled_sum, tree, out);
}

// Round 4
// 200.922 us; speedup vs baseline: 1.2381x; 1.0729x over previous
//
#include <hip/hip_runtime.h>
#include <hip/hip_bf16.h>
#include <stdint.h>

typedef __attribute__((ext_vector_type(8))) short short8;
typedef __attribute__((ext_vector_type(4))) float f32x4;

union FragU { short8 s; __hip_bfloat162 h[4]; };
union BU { uint4 u; short8 s; };

__device__ __forceinline__ unsigned short f2bf(float f) {
  union { float f; unsigned int u; } v; v.f = f;
  unsigned int r = v.u + 0x7fffu + ((v.u >> 16) & 1u);
  return (unsigned short)(r >> 16);
}

// ---------------------------------------------------------------------------
// Kernel 0: bT[e][k] = bf16( (rel @ GW)[k][e] )   (64 x 4096); zero accums.
// grid 64 x 256
// ---------------------------------------------------------------------------
__global__ void k_prep(const float* __restrict__ rel, const float* __restrict__ GW,
                       unsigned short* __restrict__ bT, float* __restrict__ accums) {
  __shared__ float tile[64][65];   // rel rows j*64..+64  [k][i]
  __shared__ float gws[64][64];    // GW [i][e]
  const int j = blockIdx.x;
  const int t = threadIdx.x;
#pragma unroll
  for (int p = 0; p < 16; ++p) {
    int elem = p * 256 + t;
    int kk = elem >> 6, ee = elem & 63;
    tile[kk][ee] = rel[(j * 64 + kk) * 64 + ee];
    ((float*)gws)[elem] = GW[elem];
  }
  __syncthreads();
  const int e = t >> 2, chunk = t & 3;
  union { unsigned short u16[16]; uint4 v[2]; } tmp;
  for (int i = 0; i < 16; ++i) {
    float acc = 0.f;
#pragma unroll
    for (int ii = 0; ii < 64; ++ii) acc += tile[chunk * 16 + i][ii] * gws[ii][e];
    tmp.u16[i] = f2bf(acc);
  }
  unsigned short* dst = bT + e * 4096 + j * 64 + chunk * 16;
  *(uint4*)(dst) = tmp.v[0];
  *(uint4*)(dst + 8) = tmp.v[1];
  if (j == 0) {
    accums[t] = 0.f; accums[t + 256] = 0.f; accums[t + 512] = 0.f; accums[t + 768] = 0.f;
  }
}

// ---------------------------------------------------------------------------
// Fused main kernel.
//   blocks 0..15      : tree attention (4 trees per block, one per wave)
//   blocks 16..4111   : split-K GEMM  partial[ks] = link[b][rows] @ relGW[kslice]
//     block = (b, ks, rb): 64 rows x 64 cols x 512 k.  B slice staged to LDS
//     once (64 KB, XOR-swizzled); barrier-free k-loop, A reg-staged nt loads.
// ---------------------------------------------------------------------------
#define NTREE 16

#define LOADA(Va, kk) do {                                            \
    const float* _ap = aptr + (kk);                                   \
    Va[0] = __builtin_nontemporal_load((const f32x4*)(_ap));          \
    Va[1] = __builtin_nontemporal_load((const f32x4*)(_ap + 4));      \
    Va[2] = __builtin_nontemporal_load((const f32x4*)(_ap + 32));     \
    Va[3] = __builtin_nontemporal_load((const f32x4*)(_ap + 36));     \
  } while (0)

#define COMPA(Va, kk) do {                                            \
    FragU f0, f1;                                                     \
    f0.h[0] = __float22bfloat162_rn(float2{Va[0][0], Va[0][1]});      \
    f0.h[1] = __float22bfloat162_rn(float2{Va[0][2], Va[0][3]});      \
    f0.h[2] = __float22bfloat162_rn(float2{Va[1][0], Va[1][1]});      \
    f0.h[3] = __float22bfloat162_rn(float2{Va[1][2], Va[1][3]});      \
    f1.h[0] = __float22bfloat162_rn(float2{Va[2][0], Va[2][1]});      \
    f1.h[1] = __float22bfloat162_rn(float2{Va[2][2], Va[2][3]});      \
    f1.h[2] = __float22bfloat162_rn(float2{Va[3][0], Va[3][1]});      \
    f1.h[3] = __float22bfloat162_rn(float2{Va[3][2], Va[3][3]});      \
    _Pragma("unroll")                                                 \
    for (int nt = 0; nt < 4; ++nt) {                                  \
      BU b0, b1;                                                      \
      b0.s = *(const short8*)(ldsb + bof[nt][0] + (kk) * 2);          \
      acc[nt] = __builtin_amdgcn_mfma_f32_16x16x32_bf16(f0.s, b0.s, acc[nt], 0, 0, 0); \
      b1.s = *(const short8*)(ldsb + bof[nt][1] + (kk) * 2);          \
      acc[nt] = __builtin_amdgcn_mfma_f32_16x16x32_bf16(f1.s, b1.s, acc[nt], 0, 0, 0); \
    }                                                                 \
  } while (0)

__global__ __launch_bounds__(256, 2) void k_main(
    const float* __restrict__ link, const unsigned short* __restrict__ bT,
    float* __restrict__ partial,
    const float* __restrict__ col_table, const float* __restrict__ rel_table,
    const float* __restrict__ Wk, const float* __restrict__ Wq, const float* __restrict__ Wv,
    const int* __restrict__ table_ids, const int* __restrict__ l_ids,
    const int* __restrict__ r_ids, float* __restrict__ tree_emb) {
  __shared__ union {
    struct { float wpk[64 * 64 * 4]; float qT[4][64][4]; } tr;  // 68 KB
    struct { unsigned short b[64 * 512]; } sb;                  // 64 KB
    struct { float c[64 * 68]; } se;                            // 17.4 KB (after k-loop)
  } sm;

  const int t = threadIdx.x;
  const int lane = t & 63;
  const int wv = t >> 6;

  if (blockIdx.x < NTREE) {
    // ------------------------- tree branch -------------------------
    const int e = lane;
#pragma unroll 4
    for (int ii = 0; ii < 16; ++ii) {
      int i = ii * 4 + wv;
      float4 w;
      w.x = Wk[i * 64 + e]; w.y = Wq[i * 64 + e]; w.z = Wv[i * 64 + e]; w.w = 0.f;
      *(float4*)&sm.tr.wpk[(i * 64 + e) * 4] = w;
    }
    __syncthreads();

    const int tree = blockIdx.x * 4 + wv;   // 0..63
    const int b = tree >> 3;
    const int* tid = table_ids + tree * 17;
    const int* lid = l_ids + tree * 32;
    const int* rid = r_ids + tree * 32;

    float prev = rel_table[tid[0] * 64 + e];

    for (int d = 0; d < 16; ++d) {
      const int l0 = lid[d * 2], l1 = lid[d * 2 + 1];
      const int r0 = rid[d * 2], r1 = rid[d * 2 + 1];
      const float lce = 0.5f * (col_table[l0 * 64 + e] + col_table[l1 * 64 + e]);
      const float rce = 0.5f * (col_table[r0 * 64 + e] + col_table[r1 * 64 + e]);
      const float rte = rel_table[tid[1 + d] * 64 + e];
      float4 qv0; qv0.x = prev; qv0.y = lce; qv0.z = rce; qv0.w = rte;
      *(float4*)&sm.tr.qT[wv][e][0] = qv0;
      __syncthreads();

      float K[4] = {0, 0, 0, 0}, Q[4] = {0, 0, 0, 0}, V[4] = {0, 0, 0, 0};
      const float* wbase = &sm.tr.wpk[e * 4];
#pragma unroll 8
      for (int i = 0; i < 64; ++i) {
        f32x4 qv = *(const f32x4*)&sm.tr.qT[wv][i][0];
        f32x4 w = *(const f32x4*)&wbase[i * 256];
#pragma unroll
        for (int j = 0; j < 4; ++j) {
          K[j] += qv[j] * w[0];
          Q[j] += qv[j] * w[1];
          V[j] += qv[j] * w[2];
        }
      }

      float sc[4][4];
#pragma unroll
      for (int j = 0; j < 4; ++j)
#pragma unroll
        for (int k = 0; k < 4; ++k) {
          float p = Q[j] * K[k];
          p += __shfl_xor(p, 1);  p += __shfl_xor(p, 2);  p += __shfl_xor(p, 4);
          p += __shfl_xor(p, 8);  p += __shfl_xor(p, 16); p += __shfl_xor(p, 32);
          sc[j][k] = p * (1.f / 64.f);
        }

      float wsum[4] = {0, 0, 0, 0};
#pragma unroll
      for (int j = 0; j < 4; ++j) {
        float mx = fmaxf(fmaxf(sc[j][0], sc[j][1]), fmaxf(sc[j][2], sc[j][3]));
        float a0 = __expf(sc[j][0] - mx), a1 = __expf(sc[j][1] - mx);
        float a2 = __expf(sc[j][2] - mx), a3 = __expf(sc[j][3] - mx);
        float inv = 1.f / (a0 + a1 + a2 + a3);
        wsum[0] += a0 * inv; wsum[1] += a1 * inv; wsum[2] += a2 * inv; wsum[3] += a3 * inv;
      }

      prev = wsum[0] * V[0] + wsum[1] * V[1] + wsum[2] * V[2] + wsum[3] * V[3];
      __syncthreads();
    }
    atomicAdd(&tree_emb[b * 64 + e], prev);
  } else {
    // ------------------------ split-K GEMM branch ------------------------
    const int sblk = blockIdx.x - NTREE;      // 0..4095
    const int b = sblk >> 9;                  // batch
    const int ks = (sblk >> 6) & 7;           // k-slice (512 k each)
    const int rb = sblk & 63;                 // row-block (64 rows)
    const int rowBase = rb * 64;
    const int wrow = wv * 16;
    const int g = lane >> 4;                  // k-group
    const int r = lane & 15;                  // row within fragment

    // ---- stage B slice (64 n x 512 k bf16) into LDS, swizzled ----
    {
      const int n = t >> 2, seg = t & 3;
      const unsigned short* src = bT + n * 4096 + ks * 512 + seg * 128;
      char* dstb = (char*)sm.sb.b;
#pragma unroll
      for (int c = 0; c < 16; ++c) {
        uint4 v = *(const uint4*)(src + c * 8);
        *(uint4*)(dstb + ((n * 1024 + seg * 256 + c * 16) ^ ((n & 7) << 4))) = v;
      }
    }
    __syncthreads();

    const float* aptr = link + ((size_t)b << 24) +
                        (size_t)(rowBase + wrow + r) * 4096 + ks * 512 + g * 8;
    const char* ldsb = (const char*)sm.sb.b;

    uint32_t bof[4][2];
#pragma unroll
    for (int nt = 0; nt < 4; ++nt)
#pragma unroll
      for (int h = 0; h < 2; ++h)
        bof[nt][h] = (uint32_t)(((nt * 16 + r) * 1024 + h * 64 + g * 16) ^ ((r & 7) << 4));

    f32x4 acc[4];
#pragma unroll
    for (int nt = 0; nt < 4; ++nt) acc[nt] = (f32x4){0.f, 0.f, 0.f, 0.f};

    f32x4 Xa[4], Ya[4];
    LOADA(Xa, 0);
#pragma unroll
    for (int kk = 0; kk < 512; kk += 128) {
      LOADA(Ya, (kk + 64) & 511);
      COMPA(Xa, kk);
      LOADA(Xa, (kk + 128) & 511);
      COMPA(Ya, kk + 64);
    }

    // ---- epilogue: C partial -> LDS -> coalesced store to ws ----
    __syncthreads();   // all waves done reading LDS B
#pragma unroll
    for (int nt = 0; nt < 4; ++nt)
#pragma unroll
      for (int j2 = 0; j2 < 4; ++j2)
        sm.se.c[(wrow + (lane >> 4) * 4 + j2) * 68 + nt * 16 + (lane & 15)] = acc[nt][j2];
    __syncthreads();
    {
      // partial flat index: ((b*4096 + row)*8 + ks)*64 + col
      float* dst = partial + (size_t)(b * 4096 + rowBase) * 512 + (size_t)ks * 64;
#pragma unroll
      for (int i = 0; i < 4; ++i) {
        int idx = t * 16 + i * 4;
        int row = idx >> 6, col = idx & 63;
        f32x4 v = *(const f32x4*)&sm.se.c[row * 68 + col];
        *(f32x4*)(dst + (size_t)row * 512 + col) = v;
      }
    }
  }
}

// ---------------------------------------------------------------------------
// Kernel 2: combine k-slices, bias+ReLU, pool columns.
// pooled_sum[b][e] += sum_rows relu( sum_ks partial + gb[e] )
// grid 512 (8 b x 64 rowblocks) x 256
// ---------------------------------------------------------------------------
__global__ void k_graph(const float* __restrict__ partial, const float* __restrict__ gbias,
                        float* __restrict__ pooled_sum) {
  __shared__ float pr[16][64];
  const int b = blockIdx.x >> 6, rb = blockIdx.x & 63;
  const int t = threadIdx.x;
  const int e4 = (t & 15) * 4;
  const int rg = t >> 4;   // 0..15, 4 rows each
  const f32x4 gb4 = *(const f32x4*)&gbias[e4];
  f32x4 accv = (f32x4){0.f, 0.f, 0.f, 0.f};
#pragma unroll
  for (int rr = 0; rr < 4; ++rr) {
    const int row = rb * 64 + rg * 4 + rr;
    const float* base = partial + (size_t)(b * 4096 + row) * 512 + e4;
    f32x4 s = (f32x4){0.f, 0.f, 0.f, 0.f};
#pragma unroll
    for (int ksl = 0; ksl < 8; ++ksl) s += *(const f32x4*)(base + ksl * 64);
    s += gb4;
#pragma unroll
    for (int c = 0; c < 4; ++c) accv[c] += fmaxf(s[c], 0.f);
  }
  *(f32x4*)&pr[rg][e4] = accv;
  __syncthreads();
  if (t < 64) {
    float ssum = 0.f;
#pragma unroll
    for (int i = 0; i < 16; ++i) ssum += pr[i][t];
    atomicAdd(&pooled_sum[b * 64 + t], ssum);
  }
}

// ---------------------------------------------------------------------------
// Kernel 3: logits = [pooled_sum/4096 || tree_emb] @ fc_w  + clip(log(mask))
// grid 128 x 256
// ---------------------------------------------------------------------------
__global__ void k_final(const float* __restrict__ action_mask, const float* __restrict__ fc_w,
                        const float* __restrict__ pooled_sum, const float* __restrict__ tree_emb,
                        float* __restrict__ out) {
  __shared__ float c[128];
  const int b = blockIdx.x >> 4;
  const int a = ((blockIdx.x & 15) << 8) + threadIdx.x;
  if (threadIdx.x < 128) {
    c[threadIdx.x] = (threadIdx.x < 64) ? pooled_sum[b * 64 + threadIdx.x] * (1.f / 4096.f)
                                        : tree_emb[b * 64 + threadIdx.x - 64];
  }
  __syncthreads();
  float acc = 0.f;
  for (int i = 0; i < 128; ++i) acc += c[i] * fc_w[i * 4096 + a];
  const float m = action_mask[b * 4096 + a];
  float lg = __logf(m);
  lg = fminf(fmaxf(lg, -3.4e38f), 3.4e38f);
  out[b * 4096 + a] = lg + acc;
}

// ---------------------------------------------------------------------------
extern "C" void kernel_launch(void* const* d_in, const int* in_sizes, int n_in,
                              void* d_out, int out_size, void* d_ws, size_t ws_size,
                              hipStream_t stream) {
  const float* link = (const float*)d_in[0];
  const float* mask = (const float*)d_in[1];
  const float* col = (const float*)d_in[2];
  const float* rel = (const float*)d_in[3];
  const float* GW = (const float*)d_in[4];
  const float* gb = (const float*)d_in[5];
  const float* Wk = (const float*)d_in[6];
  const float* Wq = (const float*)d_in[7];
  const float* Wv = (const float*)d_in[8];
  const float* fcw = (const float*)d_in[9];
  const int* tids = (const int*)d_in[10];
  const int* lids = (const int*)d_in[11];
  const int* rids = (const int*)d_in[12];
  float* out = (float*)d_out;

  unsigned short* bT = (unsigned short*)d_ws;               // 512 KB  (relGW^T bf16)
  float* accums = (float*)((char*)d_ws + 512 * 1024);       // 1024 floats
  float* pooled_sum = accums;                               // [8][64]
  float* tree = accums + 512;                               // [8][64]
  float* partial = (float*)((char*)d_ws + 1024 * 1024);     // 64 MB: [b][row][ks][64]

  hipLaunchKernelGGL(k_prep, dim3(64), dim3(256), 0, stream, rel, GW, bT, accums);
  hipLaunchKernelGGL(k_main, dim3(NTREE + 4096), dim3(256), 0, stream,
                     link, bT, partial,
                     col, rel, Wk, Wq, Wv, tids, lids, rids, tree);
  hipLaunchKernelGGL(k_graph, dim3(512), dim3(256), 0, stream, partial, gb, pooled_sum);
  hipLaunchKernelGGL(k_final, dim3(128), dim3(256), 0, stream, mask, fcw, pooled_sum, tree, out);
}